// Round 5
// baseline (798.095 us; speedup 1.0000x reference)
//
#include <hip/hip_runtime.h>
#include <math.h>

#define NBR 4
#define NLAY 3
#define Bk 4
#define Tk 1024
#define DIN 32
#define DMODEL 128
#define DINNER 256
#define DSTATE 16
#define DTRANK 8
#define EMBEDk 64
#define BT (Bk*Tk)          /* 4096 rows per branch */
#define EPSF 1e-7f
#define MAXNF 10.0f
#define LCH 64              /* scan chunk length */
#define NCH (Tk/LCH)        /* 16 chunks */
#define UF 8                /* t-loop batch (latency amortization) */
#define NWC 384             /* padded dt|bc weight panel width */

__device__ __forceinline__ float siluf(float x){ return x / (1.f + __expf(-x)); }
__device__ __forceinline__ float softplusf(float x){ return (x > 20.f) ? x : log1pf(__expf(x)); }

// dA[s] = q^(s+1) from q (A_s = -(s+1) fast path)
__device__ __forceinline__ void dA_pow(float q, float* dA){
    dA[0] = q;             dA[1] = q * q;
    dA[2] = dA[1] * dA[0]; dA[3] = dA[1] * dA[1];
    dA[4] = dA[3] * dA[0]; dA[5] = dA[3] * dA[1];
    dA[6] = dA[3] * dA[2]; dA[7] = dA[3] * dA[3];
    #pragma unroll
    for (int s = 8; s < 16; ++s) dA[s] = dA[s - 8] * dA[7];
}
// generic fallback: dA[s] = exp(dtv * Aa[s])
__device__ __forceinline__ void dA_exp(float dtv, const float* Aa, float* dA){
    #pragma unroll
    for (int s = 0; s < 16; ++s) dA[s] = __expf(dtv * Aa[s]);
}

// ---------------------------------------------------------------------------
// fp32 SGEMM: C = A(MxK) @ B(KxN), 128x128 tile, Kc=32, 8x8 per thread.
// MODE 0: xz  -> n0<256: raw to C0 (xp); n0>=256: silu to C1 (z)
// MODE 1: plain store to C0 (ldc)
// MODE 2: input proj -> +bias; A selected from {A,A1,A2,A3} by blockIdx.z
// MODE 3: dt|bc -> n0<256: softplus(v+bias) to C0 (dt, ld 256);
//                  n0==256: cols 256..287 raw to C1 (bc, ld 32); rest dropped
// M mult of 128, N mult of 128, K mult of 32.
// ---------------------------------------------------------------------------
template<int MODE>
__global__ __launch_bounds__(256) void sgemm2_k(
    const float* __restrict__ A,  const float* __restrict__ A1,
    const float* __restrict__ A2, const float* __restrict__ A3,
    int lda, long aBr,
    const float* __restrict__ Bw, int ldb, long bBr,
    float* __restrict__ C0, long cBr,
    float* __restrict__ C1, long c1Br, int ldc,
    const float* __restrict__ bias, long biasBr, int K)
{
    const int br = blockIdx.z;
    if (MODE == 2) {
        A = (br == 1) ? A1 : (br == 2) ? A2 : (br == 3) ? A3 : A;
    } else {
        A += (long)br * aBr;
    }
    Bw += (long)br * bBr;
    C0 += (long)br * cBr;
    if (MODE == 0 || MODE == 3) C1 += (long)br * c1Br;
    if (MODE == 2 || MODE == 3) bias += (long)br * biasBr;
    const int m0 = blockIdx.x * 128, n0 = blockIdx.y * 128;
    __shared__ float As[32][132];   // [k][m]
    __shared__ float Bs[32][132];   // [k][n]
    const int tid = threadIdx.x;
    const int tx = tid & 15, ty = tid >> 4;
    float acc[8][8] = {};
    for (int kc = 0; kc < K; kc += 32) {
        #pragma unroll
        for (int it = 0; it < 4; ++it) {
            int id = tid + it * 256;
            int r = id >> 3, c4 = (id & 7) << 2;
            float4 v = *(const float4*)(A + (long)(m0 + r) * lda + kc + c4);
            As[c4+0][r] = v.x; As[c4+1][r] = v.y; As[c4+2][r] = v.z; As[c4+3][r] = v.w;
            int rb = id >> 5, cb = (id & 31) << 2;
            *(float4*)&Bs[rb][cb] = *(const float4*)(Bw + (long)(kc + rb) * ldb + n0 + cb);
        }
        __syncthreads();
        #pragma unroll
        for (int kk = 0; kk < 32; ++kk) {
            float a[8], b[8];
            *(float4*)&a[0] = *(const float4*)&As[kk][ty * 8];
            *(float4*)&a[4] = *(const float4*)&As[kk][ty * 8 + 4];
            *(float4*)&b[0] = *(const float4*)&Bs[kk][tx * 8];
            *(float4*)&b[4] = *(const float4*)&Bs[kk][tx * 8 + 4];
            #pragma unroll
            for (int i = 0; i < 8; ++i)
                #pragma unroll
                for (int j = 0; j < 8; ++j)
                    acc[i][j] = fmaf(a[i], b[j], acc[i][j]);
        }
        __syncthreads();
    }
    const int col0 = n0 + tx * 8;
    float bs[8];
    if (MODE == 2 || (MODE == 3 && n0 < 256)) {
        #pragma unroll
        for (int j = 0; j < 8; ++j) bs[j] = bias[col0 + j];
    }
    #pragma unroll
    for (int i = 0; i < 8; ++i) {
        const int row = m0 + ty * 8 + i;
        float v[8];
        #pragma unroll
        for (int j = 0; j < 8; ++j) v[j] = acc[i][j];
        if (MODE == 2) {
            #pragma unroll
            for (int j = 0; j < 8; ++j) v[j] += bs[j];
        }
        if (MODE == 0 && n0 >= 256) {
            #pragma unroll
            for (int j = 0; j < 8; ++j) v[j] = siluf(v[j]);
        }
        if (MODE == 3 && n0 < 256) {
            #pragma unroll
            for (int j = 0; j < 8; ++j) v[j] = softplusf(v[j] + bs[j]);
        }
        float4 v0; v0.x = v[0]; v0.y = v[1]; v0.z = v[2]; v0.w = v[3];
        float4 v1; v1.x = v[4]; v1.y = v[5]; v1.z = v[6]; v1.w = v[7];
        if (MODE == 0) {
            float* dst = (n0 < 256) ? (C0 + (long)row * DINNER + col0)
                                    : (C1 + (long)row * DINNER + (col0 - 256));
            *(float4*)dst = v0; *(float4*)(dst + 4) = v1;
        } else if (MODE == 1 || MODE == 2) {
            float* dst = C0 + (long)row * ldc + col0;
            *(float4*)dst = v0; *(float4*)(dst + 4) = v1;
        } else {
            if (n0 < 256) {
                float* dst = C0 + (long)row * 256 + col0;
                *(float4*)dst = v0; *(float4*)(dst + 4) = v1;
            } else if (tx < 4) {
                float* dst = C1 + (long)row * 32 + (col0 - 256);
                *(float4*)dst = v0; *(float4*)(dst + 4) = v1;
            }
        }
    }
}

// ---------------------------------------------------------------------------
// prep: per (br, layer) build padded weight panel wc (256 x 384):
//   cols 0..255  = Wx[:, :8] @ Wdt   (so dt = softplus(xc @ wc[:, :256] + b_dt))
//   cols 256..287 = Wx[:, 8:40]      (B,C)
//   cols 288..383 = 0
// grid (NBR, 4 k-quads), 256 threads (one output col each, +1 padded col).
// ---------------------------------------------------------------------------
__global__ __launch_bounds__(256) void prep_k(
    const float* __restrict__ Wx, const float* __restrict__ Wdt,
    float* __restrict__ wc, int layer)
{
    const int br = blockIdx.x, kq = blockIdx.y;
    const int j = threadIdx.x;
    const float* WxP  = Wx  + (long)(br * NLAY + layer) * DINNER * 40;
    const float* WdtP = Wdt + (long)(br * NLAY + layer) * DTRANK * DINNER;
    __shared__ float wxs[64][8];
    for (int idx = j; idx < 512; idx += 256) {
        int k = idx >> 3, r = idx & 7;
        wxs[k][r] = WxP[(long)(kq * 64 + k) * 40 + r];
    }
    float wdt[8];
    #pragma unroll
    for (int r = 0; r < 8; ++r) wdt[r] = WdtP[r * DINNER + j];
    __syncthreads();
    float* outp = wc + (long)br * (256 * NWC) + (long)kq * 64 * NWC;
    for (int k = 0; k < 64; ++k) {
        float acc = 0.f;
        #pragma unroll
        for (int r = 0; r < 8; ++r) acc = fmaf(wxs[k][r], wdt[r], acc);
        outp[k * NWC + j] = acc;
        if (j < 128) {
            int kg = kq * 64 + k;
            outp[k * NWC + 256 + j] = (j < 32) ? WxP[(long)kg * 40 + 8 + j] : 0.f;
        }
    }
}

// ---------------------------------------------------------------------------
// Depthwise causal conv (4 taps) + bias + silu.
// ---------------------------------------------------------------------------
__global__ __launch_bounds__(256) void conv_k(
    const float* __restrict__ xp, const float* __restrict__ cw,
    const float* __restrict__ cb, float* __restrict__ xc, int layer)
{
    const int br = blockIdx.y;
    const long base = (long)br * BT * DINNER;
    const int idx = blockIdx.x * 256 + threadIdx.x;
    const int d = idx & (DINNER - 1);
    const int row = idx >> 8;
    const int t = row & (Tk - 1);
    const float4 w4 = *(const float4*)(cw + ((long)(br * NLAY + layer) * DINNER + d) * 4);
    const float wv[4] = {w4.x, w4.y, w4.z, w4.w};
    float acc = cb[(br * NLAY + layer) * DINNER + d];
    const float* xpb = xp + base + idx;
    #pragma unroll
    for (int k = 0; k < 4; ++k) {
        int tt = t + k - 3;
        if (tt >= 0) acc = fmaf(xpb[(long)(k - 3) * DINNER], wv[k], acc);
    }
    xc[base + idx] = siluf(acc);
}

// ---------------------------------------------------------------------------
// Scan pass 1: per-chunk local recurrence from h=0 -> record (h_end[16], sumdt).
// ---------------------------------------------------------------------------
__global__ __launch_bounds__(256) void scan1_k(
    const float* __restrict__ dtb, const float* __restrict__ xcb,
    const float* __restrict__ bcb, const float* __restrict__ Alog,
    float* __restrict__ recbuf, int layer)
{
    const int c = blockIdx.x, b = blockIdx.y, br = blockIdx.z;
    const int d = threadIdx.x;
    const float* Ap = Alog + ((long)(br * NLAY + layer) * DINNER + d) * DSTATE;
    float Aa[16];
    bool pw = true;
    #pragma unroll
    for (int s = 0; s < 16; ++s) {
        Aa[s] = -__expf(Ap[s]);
        pw = pw && (fabsf(Aa[s] + (float)(s + 1)) < 1e-3f);
    }
    const long rbase = (long)br * BT + (long)b * Tk + (long)c * LCH;
    const float* dtp = dtb + rbase * DINNER + d;
    const float* xcp = xcb + rbase * DINNER + d;
    __shared__ float bcs[LCH * 32];      // 8 KB
    {
        const float4* g = (const float4*)(bcb + rbase * 32);
        float4* l = (float4*)bcs;
        l[d] = g[d]; l[d + 256] = g[d + 256];
    }
    float dtc[UF], xcc[UF];
    #pragma unroll
    for (int u = 0; u < UF; ++u) {
        dtc[u] = dtp[(long)u * DINNER];
        xcc[u] = xcp[(long)u * DINNER];
    }
    __syncthreads();
    float h[16];
    #pragma unroll
    for (int s = 0; s < 16; ++s) h[s] = 0.f;
    float sumdt = 0.f;
    for (int base = 0; base < LCH; base += UF) {
        const int nb = (base + UF < LCH) ? base + UF : base;
        float dtn[UF], xcn[UF];
        #pragma unroll
        for (int u = 0; u < UF; ++u) {
            dtn[u] = dtp[(long)(nb + u) * DINNER];
            xcn[u] = xcp[(long)(nb + u) * DINNER];
        }
        #pragma unroll
        for (int u = 0; u < UF; ++u) {
            const int t = base + u;
            const float dtv = dtc[u];
            const float dtxc = dtv * xcc[u];
            sumdt += dtv;
            float dA[16];
            if (pw) dA_pow(__expf(-dtv), dA);
            else    dA_exp(dtv, Aa, dA);
            const float* bcT = bcs + t * 32;     // uniform addr -> broadcast
            #pragma unroll
            for (int s = 0; s < 16; ++s)
                h[s] = fmaf(dA[s], h[s], dtxc * bcT[s]);
        }
        #pragma unroll
        for (int u = 0; u < UF; ++u) { dtc[u] = dtn[u]; xcc[u] = xcn[u]; }
    }
    float* sb = recbuf + (((long)(br * 4 + b) * (NCH - 1) + c) * 17) * 256 + d;
    #pragma unroll
    for (int s = 0; s < 16; ++s) sb[s * 256] = h[s];
    sb[16 * 256] = sumdt;
}

// ---------------------------------------------------------------------------
// Scan pass 2: sequential fold over chunk records -> chunk-start carries.
// ---------------------------------------------------------------------------
__global__ __launch_bounds__(256) void scan2_k(
    const float* __restrict__ Alog, const float* __restrict__ recbuf,
    float* __restrict__ carbuf, int layer)
{
    const int br = blockIdx.x >> 2, b = blockIdx.x & 3;
    const int d = threadIdx.x;
    const float* Ap = Alog + ((long)(br * NLAY + layer) * DINNER + d) * DSTATE;
    float Aa[16];
    bool pw = true;
    #pragma unroll
    for (int s = 0; s < 16; ++s) {
        Aa[s] = -__expf(Ap[s]);
        pw = pw && (fabsf(Aa[s] + (float)(s + 1)) < 1e-3f);
    }
    const float* recB = recbuf + ((long)(br * 4 + b) * (NCH - 1)) * 17 * 256 + d;
    float* carB = carbuf + ((long)(br * 4 + b) * NCH) * 16 * 256 + d;
    float h[16];
    #pragma unroll
    for (int s = 0; s < 16; ++s) h[s] = 0.f;
    float rh[16], rs;
    #pragma unroll
    for (int s = 0; s < 16; ++s) rh[s] = recB[s * 256];
    rs = recB[16 * 256];
    for (int c = 0; c < NCH; ++c) {
        float* car = carB + (long)c * 16 * 256;
        #pragma unroll
        for (int s = 0; s < 16; ++s) car[s * 256] = h[s];
        if (c < NCH - 1) {
            float nh[16], ns = 0.f;
            if (c + 1 < NCH - 1) {
                const float* r2 = recB + (long)(c + 1) * 17 * 256;
                #pragma unroll
                for (int s = 0; s < 16; ++s) nh[s] = r2[s * 256];
                ns = r2[16 * 256];
            } else {
                #pragma unroll
                for (int s = 0; s < 16; ++s) nh[s] = 0.f;
            }
            float P[16];
            if (pw) dA_pow(__expf(-rs), P);
            else    dA_exp(rs, Aa, P);
            #pragma unroll
            for (int s = 0; s < 16; ++s) h[s] = fmaf(h[s], P[s], rh[s]);
            #pragma unroll
            for (int s = 0; s < 16; ++s) rh[s] = nh[s];
            rs = ns;
        }
    }
}

// ---------------------------------------------------------------------------
// Scan pass 3: carry + local recurrence; yz = (y + Dp*xc)*silu(z).
// ---------------------------------------------------------------------------
__global__ __launch_bounds__(256) void scan3_k(
    const float* __restrict__ dtb, const float* __restrict__ xcb,
    const float* __restrict__ bcb, const float* __restrict__ zb,
    const float* __restrict__ Alog, const float* __restrict__ Dpar,
    const float* __restrict__ carbuf, float* __restrict__ yz, int layer)
{
    const int c = blockIdx.x, b = blockIdx.y, br = blockIdx.z;
    const int d = threadIdx.x;
    const float* car = carbuf + (((long)(br * 4 + b) * NCH + c) * 16) * 256 + d;
    float h[16];
    #pragma unroll
    for (int s = 0; s < 16; ++s) h[s] = car[s * 256];
    const float* Ap = Alog + ((long)(br * NLAY + layer) * DINNER + d) * DSTATE;
    float Aa[16];
    bool pw = true;
    #pragma unroll
    for (int s = 0; s < 16; ++s) {
        Aa[s] = -__expf(Ap[s]);
        pw = pw && (fabsf(Aa[s] + (float)(s + 1)) < 1e-3f);
    }
    const float Dp = Dpar[(br * NLAY + layer) * DINNER + d];
    const long rbase = (long)br * BT + (long)b * Tk + (long)c * LCH;
    const float* dtp = dtb + rbase * DINNER + d;
    const float* xcp = xcb + rbase * DINNER + d;
    const float* zp  = zb  + rbase * DINNER + d;
    float*       yp  = yz  + rbase * DINNER + d;
    __shared__ float bcs[LCH * 32];      // 8 KB
    {
        const float4* g = (const float4*)(bcb + rbase * 32);
        float4* l = (float4*)bcs;
        l[d] = g[d]; l[d + 256] = g[d + 256];
    }
    float dtc[UF], xcc[UF], zc[UF];
    #pragma unroll
    for (int u = 0; u < UF; ++u) {
        dtc[u] = dtp[(long)u * DINNER];
        xcc[u] = xcp[(long)u * DINNER];
        zc[u]  = zp[(long)u * DINNER];
    }
    __syncthreads();
    for (int base = 0; base < LCH; base += UF) {
        const int nb = (base + UF < LCH) ? base + UF : base;
        float dtn[UF], xcn[UF], zn[UF];
        #pragma unroll
        for (int u = 0; u < UF; ++u) {
            dtn[u] = dtp[(long)(nb + u) * DINNER];
            xcn[u] = xcp[(long)(nb + u) * DINNER];
            zn[u]  = zp[(long)(nb + u) * DINNER];
        }
        #pragma unroll
        for (int u = 0; u < UF; ++u) {
            const int t = base + u;
            const float dtv = dtc[u], xcv = xcc[u];
            const float dtxc = dtv * xcv;
            float dA[16];
            if (pw) dA_pow(__expf(-dtv), dA);
            else    dA_exp(dtv, Aa, dA);
            const float* bcT = bcs + t * 32;     // uniform addr -> broadcast
            #pragma unroll
            for (int s = 0; s < 16; ++s)
                h[s] = fmaf(dA[s], h[s], dtxc * bcT[s]);
            float y0 = 0.f, y1 = 0.f, y2 = 0.f, y3 = 0.f;
            #pragma unroll
            for (int s = 0; s < 16; s += 4) {
                y0 = fmaf(h[s+0], bcT[16+s+0], y0);
                y1 = fmaf(h[s+1], bcT[16+s+1], y1);
                y2 = fmaf(h[s+2], bcT[16+s+2], y2);
                y3 = fmaf(h[s+3], bcT[16+s+3], y3);
            }
            const float y = (y0 + y1) + (y2 + y3) + Dp * xcv;
            yp[(long)t * DINNER] = y * zc[u];
        }
        #pragma unroll
        for (int u = 0; u < UF; ++u) { dtc[u] = dtn[u]; xcc[u] = xcn[u]; zc[u] = zn[u]; }
    }
}

// ---------------------------------------------------------------------------
// mean over T then @ W_op + b_op -> z_t directly into d_out[0..1023].
// ---------------------------------------------------------------------------
__global__ __launch_bounds__(128) void meanop_k(
    const float* __restrict__ hbuf, const float* __restrict__ Wop,
    const float* __restrict__ bop, float* __restrict__ outzt)
{
    const int br = blockIdx.x >> 2, b = blockIdx.x & 3;
    const int tid = threadIdx.x;
    const float* hp = hbuf + ((long)br * BT + (long)b * Tk) * DMODEL + tid;
    float s = 0.f;
    for (int t = 0; t < Tk; ++t) s += hp[(long)t * DMODEL];
    __shared__ float hm[DMODEL];
    hm[tid] = s * (1.0f / Tk);
    __syncthreads();
    if (tid < EMBEDk) {
        float acc = bop[br * EMBEDk + tid];
        for (int k = 0; k < DMODEL; ++k)
            acc = fmaf(hm[k], Wop[(long)br * DMODEL * EMBEDk + k * EMBEDk + tid], acc);
        outzt[br * (Bk * EMBEDk) + b * EMBEDk + tid] = acc;
    }
}

// ---------------------------------------------------------------------------
// Lorentz epilogue.
// ---------------------------------------------------------------------------
__global__ __launch_bounds__(64) void final_k(
    const float* __restrict__ zt, float* __restrict__ out, const float* __restrict__ eff)
{
    const float es = tanhf(eff[0]);
    __shared__ float us[NBR][Bk][EMBEDk];
    const int t = threadIdx.x;
    if (t < 16) {
        const int br = t >> 2, b = t & 3;
        const float* z = zt + br * (Bk * EMBEDk) + b * EMBEDk;
        float n2 = 0.f;
        for (int e = 0; e < EMBEDk; ++e) { float v = z[e] * es; n2 = fmaf(v, v, n2); }
        const float n  = sqrtf(n2);
        const float nc = fminf(fmaxf(n, EPSF), MAXNF);
        const float sc = nc / fmaxf(n, EPSF);
        const float sh = sinhf(nc) / nc;
        const float fac = es * sc * sh;
        float* zh = out + 1024 + br * (Bk * (EMBEDk + 1)) + b * (EMBEDk + 1);
        float sp2 = 0.f;
        for (int e = 0; e < EMBEDk; ++e) {
            float spv = z[e] * fac;
            sp2 = fmaf(spv, spv, sp2);
            zh[1 + e] = spv;
            us[br][b][e] = spv;
        }
        const float t0 = sqrtf(1.f + sp2);
        zh[0] = t0;
        const float dd  = acoshf(fmaxf(t0, 1.f + EPSF));
        const float spn = fmaxf(sqrtf(sp2), EPSF);
        const float rr  = dd / spn;
        for (int e = 0; e < EMBEDk; ++e) us[br][b][e] *= rr;
    }
    __syncthreads();
    if (t < 4) {
        const int b = t;
        float ct[EMBEDk];
        float* cto = out + 2064 + b * EMBEDk;
        for (int e = 0; e < EMBEDk; ++e) {
            float v = us[0][b][e] + us[1][b][e] + us[2][b][e] + us[3][b][e];
            ct[e] = v; cto[e] = v;
        }
        float n2 = 0.f;
        for (int e = 0; e < EMBEDk; ++e) { float v = ct[e] * es; n2 = fmaf(v, v, n2); }
        const float n  = sqrtf(n2);
        const float nc = fminf(fmaxf(n, EPSF), MAXNF);
        const float sc = nc / fmaxf(n, EPSF);
        const float sh = sinhf(nc) / nc;
        const float fac = es * sc * sh;
        float* ch = out + 2320 + b * (EMBEDk + 1);
        float sp2 = 0.f;
        for (int e = 0; e < EMBEDk; ++e) {
            float spv = ct[e] * fac;
            sp2 = fmaf(spv, spv, sp2);
            ch[1 + e] = spv;
        }
        ch[0] = sqrtf(1.f + sp2);
    }
}

extern "C" void kernel_launch(void* const* d_in, const int* in_sizes, int n_in,
                              void* d_out, int out_size, void* d_ws, size_t ws_size,
                              hipStream_t stream)
{
    const float* X0 = (const float*)d_in[0];
    const float* X1 = (const float*)d_in[1];
    const float* X2 = (const float*)d_in[2];
    const float* X3 = (const float*)d_in[3];
    const float* W_ip   = (const float*)d_in[4];
    const float* b_ip   = (const float*)d_in[5];
    const float* W_in   = (const float*)d_in[6];
    const float* conv_w = (const float*)d_in[7];
    const float* conv_b = (const float*)d_in[8];
    const float* W_x    = (const float*)d_in[9];
    const float* W_dt   = (const float*)d_in[10];
    const float* b_dt   = (const float*)d_in[11];
    const float* A_log  = (const float*)d_in[12];
    const float* D_par  = (const float*)d_in[13];
    const float* W_out  = (const float*)d_in[14];
    const float* W_op   = (const float*)d_in[15];
    const float* b_op   = (const float*)d_in[16];
    const float* eff    = (const float*)d_in[17];
    float* out = (float*)d_out;
    float* ws  = (float*)d_ws;

    // workspace layout (floats), ~78 MB
    float* buf_h  = ws;                                  // 4*4096*128 = 2.097M
    float* buf_xp = buf_h  + (long)NBR * BT * DMODEL;    // 4*4096*256 (xp / wc panel / yz)
    float* buf_z  = buf_xp + (long)NBR * BT * DINNER;
    float* buf_xc = buf_z  + (long)NBR * BT * DINNER;
    float* buf_dt = buf_xc + (long)NBR * BT * DINNER;
    float* buf_bc = buf_dt + (long)NBR * BT * DINNER;    // 4*4096*32
    // scan records + carries alias buf_h (dead between xz-GEMM and W_out-GEMM)
    float* recbuf = buf_h;
    float* carbuf = buf_h + (long)16 * (NCH - 1) * 17 * 256;
    // dt|bc weight panel aliases buf_xp (xp dead after conv; yz written later):
    // 4 * 256 * 384 = 393216 floats << 4.19M  ✓
    float* wcomb = buf_xp;

    // input projection, all branches in one dispatch: h0 = x @ W_ip + b_ip
    sgemm2_k<2><<<dim3(BT / 128, 1, NBR), 256, 0, stream>>>(
        X0, X1, X2, X3, DIN, 0,
        W_ip, DMODEL, (long)DIN * DMODEL,
        buf_h, (long)BT * DMODEL, nullptr, 0, DMODEL,
        b_ip, DMODEL, DIN);

    for (int l = 0; l < NLAY; ++l) {
        // xz = h @ W_in; split -> xp, silu(z)
        sgemm2_k<0><<<dim3(BT / 128, (2 * DINNER) / 128, NBR), 256, 0, stream>>>(
            buf_h, nullptr, nullptr, nullptr, DMODEL, (long)BT * DMODEL,
            W_in + (long)l * DMODEL * 2 * DINNER, 2 * DINNER,
            (long)NLAY * DMODEL * 2 * DINNER,
            buf_xp, (long)BT * DINNER, buf_z, (long)BT * DINNER, DINNER,
            nullptr, 0, DMODEL);
        // depthwise conv + silu
        conv_k<<<dim3((BT * DINNER) / 256, NBR), 256, 0, stream>>>(
            buf_xp, conv_w, conv_b, buf_xc, l);
        // build dt|bc weight panel (into buf_xp, xp now dead)
        prep_k<<<dim3(NBR, 4), 256, 0, stream>>>(W_x, W_dt, wcomb, l);
        // dt = softplus(xc @ wc[:,:256] + b_dt); bc = xc @ wc[:,256:288]
        sgemm2_k<3><<<dim3(BT / 128, NWC / 128, NBR), 256, 0, stream>>>(
            buf_xc, nullptr, nullptr, nullptr, DINNER, (long)BT * DINNER,
            wcomb, NWC, (long)256 * NWC,
            buf_dt, (long)BT * DINNER, buf_bc, (long)BT * 32, DINNER,
            b_dt + l * DINNER, (long)NLAY * DINNER, DINNER);
        // chunked scan: local records -> carry scan -> local w/ carry
        scan1_k<<<dim3(NCH - 1, Bk, NBR), 256, 0, stream>>>(
            buf_dt, buf_xc, buf_bc, A_log, recbuf, l);
        scan2_k<<<16, 256, 0, stream>>>(A_log, recbuf, carbuf, l);
        scan3_k<<<dim3(NCH, Bk, NBR), 256, 0, stream>>>(
            buf_dt, buf_xc, buf_bc, buf_z, A_log, D_par, carbuf, buf_xp, l);
        // h = yz @ W_out
        sgemm2_k<1><<<dim3(BT / 128, DMODEL / 128, NBR), 256, 0, stream>>>(
            buf_xp, nullptr, nullptr, nullptr, DINNER, (long)BT * DINNER,
            W_out + (long)l * DINNER * DMODEL, DMODEL,
            (long)NLAY * DINNER * DMODEL,
            buf_h, (long)BT * DMODEL, nullptr, 0, DMODEL,
            nullptr, 0, DINNER);
    }

    meanop_k<<<16, 128, 0, stream>>>(buf_h, W_op, b_op, out);
    final_k<<<1, 64, 0, stream>>>(out, out, eff);
}